// Round 7
// baseline (400.915 us; speedup 1.0000x reference)
//
#include <hip/hip_runtime.h>
#include <hip/hip_bf16.h>
#include <stdint.h>

// ---------------- problem constants ----------------
#define N_NODES 16384
#define D_IN    256
#define D_OUT   256
#define K_SAMP  10
#define HALF_FLAT (1u << 27)

// JAX PRNG mode: 1 = jax_threefry_partitionable (verified correct R3-R6).
#define JAX_PARTITIONABLE 1

typedef __attribute__((ext_vector_type(4))) float  f32x4;

__device__ __forceinline__ uint32_t rotl32(uint32_t x, int r) {
    return (x << r) | (x >> (32 - r));
}

// Exact replica of jax threefry2x32 noise bits for flat index i = r*16384 + c, key (0,42).
__device__ __forceinline__ uint32_t jax_noise_bits(uint32_t r, uint32_t c) {
    const uint32_t i  = (r << 14) | c;
    const uint32_t k0 = 0u, k1 = 42u;
    const uint32_t k2 = 42u ^ 0x1BD11BDAu;
    uint32_t x0, x1;
#if JAX_PARTITIONABLE
    x0 = 0u;
    x1 = i;
#else
    const bool lo = (i < HALF_FLAT);
    x0 = lo ? i : (i - HALF_FLAT);
    x1 = lo ? (i + HALF_FLAT) : i;
#endif
    x0 += k0; x1 += k1;
#define TFR4(a,b,cc,d) \
    x0 += x1; x1 = rotl32(x1,a);  x1 ^= x0; \
    x0 += x1; x1 = rotl32(x1,b);  x1 ^= x0; \
    x0 += x1; x1 = rotl32(x1,cc); x1 ^= x0; \
    x0 += x1; x1 = rotl32(x1,d);  x1 ^= x0;
    TFR4(13,15,26,6);   x0 += k1; x1 += k2 + 1u;
    TFR4(17,29,16,24);  x0 += k2; x1 += k0 + 2u;
    TFR4(13,15,26,6);   x0 += k0; x1 += k1 + 3u;
    TFR4(17,29,16,24);  x0 += k1; x1 += k2 + 4u;
    TFR4(13,15,26,6);   x0 += k2; x1 += k0 + 5u;
#undef TFR4
#if JAX_PARTITIONABLE
    return x0 ^ x1;
#else
    return (i < HALF_FLAT) ? x0 : x1;
#endif
}

__device__ __forceinline__ unsigned short f2bfbits(float f) {
    __hip_bfloat16 h = __float2bfloat16(f);
    return *(unsigned short*)&h;
}

// ---------------- kernel T: W f32 [256][512] → Wt bf16 [512][256] (transpose+cvt) -------
// 32x32 LDS tile transpose, +1 pad. Block (32,8), grid (512/32, 256/32).
__global__ __launch_bounds__(256) void k_transw(const float* __restrict__ W,
                                                unsigned short* __restrict__ Wt)
{
    __shared__ float tile[32][33];
    const int tx = threadIdx.x;       // 0..31
    const int ty = threadIdx.y;       // 0..7
    const int kb = blockIdx.x * 32;   // k tile base (0..511)
    const int nb = blockIdx.y * 32;   // n tile base (0..255)

    #pragma unroll
    for (int i = 0; i < 4; ++i) {
        int n = ty + 8 * i;           // n_local
        tile[n][tx] = W[(size_t)(nb + n) * 512 + kb + tx];   // coalesced in tx
    }
    __syncthreads();
    #pragma unroll
    for (int i = 0; i < 4; ++i) {
        int k = ty + 8 * i;           // k_local
        // Wt[kb+k][nb+tx] = W[nb+tx][kb+k] = tile[tx][k]; stride-33 read: conflict-free
        Wt[(size_t)(kb + k) * 256 + nb + tx] = f2bfbits(tile[tx][k]);
    }
}

// ---------------- fused kernel: sample + aggregate + linear + relu → out f32 ------------
// 4 waves/block, each wave owns one node; ALL LDS is wave-private → zero barriers.
// Phases: (1) nt-stream adjacency row, ballot-compact nonzero cols; (2) dense threefry
// (≤2 evals/lane); (3) register top-10 via wave-argmax + coalesced x gathers;
// (4) stage h=[x|agg] f32 in LDS row; (5) epilogue: lane computes 4 out cols with
// coalesced bf16 Wt reads; bias+relu; nt-store f32x4 to d_out.
__global__ __launch_bounds__(256) void k_fused(
    const float* __restrict__ x, const float* __restrict__ adj,
    const unsigned short* __restrict__ Wt, const float* __restrict__ bias,
    float* __restrict__ out)
{
    const int t    = threadIdx.x;
    const int lane = t & 63;
    const int w    = t >> 6;
    const int r    = blockIdx.x * 4 + w;

    __shared__ unsigned short candc[4][128];   // wave-private nonzero-column list
    __shared__ float hL[4][512];               // wave-private h row (f32)

    // ---- (1) stream + compact (non-temporal adjacency reads) ----
    const f32x4* rowp = (const f32x4*)(adj + (size_t)r * N_NODES);
    int nc = 0;                                 // wave-uniform candidate count
    #pragma unroll 8
    for (int it = 0; it < 64; ++it) {
        f32x4 v = __builtin_nontemporal_load(rowp + it * 64 + lane);
        int cb = (it * 64 + lane) * 4;
        #pragma unroll
        for (int j = 0; j < 4; ++j) {
            unsigned long long mask = __ballot(v[j] != 0.0f);
            if (mask) {
                if (v[j] != 0.0f) {
                    int below = __builtin_amdgcn_mbcnt_hi(
                        (uint32_t)(mask >> 32),
                        __builtin_amdgcn_mbcnt_lo((uint32_t)mask, 0));
                    int slot = nc + below;
                    if (slot < 128) candc[w][slot] = (unsigned short)(cb + j);
                }
                nc += __popcll(mask);
            }
        }
    }
    if (nc > 128) nc = 128;                     // P(deg>128) ~ 0 (17 sigma)

    // ---- (2) dense threefry: keys for candidates lane and lane+64 ----
    unsigned long long k0 = 0ull, k1 = 0ull;
    if (lane < nc) {
        uint32_t c   = candc[w][lane];
        uint32_t u23 = jax_noise_bits((uint32_t)r, c) >> 9;   // monotone with uniform float
        k0 = ((((unsigned long long)u23) << 14) | (unsigned long long)(16383u - c)) + 1ull;
    }
    if (64 + lane < nc) {
        uint32_t c   = candc[w][64 + lane];
        uint32_t u23 = jax_noise_bits((uint32_t)r, c) >> 9;
        k1 = ((((unsigned long long)u23) << 14) | (unsigned long long)(16383u - c)) + 1ull;
    }

    // ---- (3) top-K selection (register space) + gather ----
    const int m = nc < K_SAMP ? nc : K_SAMP;
    f32x4 acc = {0.f, 0.f, 0.f, 0.f};
    for (int s = 0; s < m; ++s) {
        unsigned long long my = k0 > k1 ? k0 : k1;
        #pragma unroll
        for (int o = 1; o < 64; o <<= 1) {
            unsigned long long other = __shfl_xor(my, o);
            if (other > my) my = other;
        }
        // keys unique (low 14 bits = distinct column) -> exactly one lane/slot matches
        if (k0 == my) k0 = 0ull; else if (k1 == my) k1 = 0ull;
        const int col = 16383 - (int)((my - 1ull) & 0x3FFFull);
        f32x4 xv = *(const f32x4*)(x + (size_t)col * D_IN + lane * 4);
        acc += xv;
    }
    const float inv = (m > 0) ? 1.0f / (float)m : 0.0f;

    // ---- (4) stage h row = [self | agg] f32 (wave-private; no barrier needed) ----
    f32x4 sv = *(const f32x4*)(x + (size_t)r * D_IN + lane * 4);
    *(f32x4*)&hL[w][lane * 4]         = sv;
    f32x4 av = acc * inv;
    *(f32x4*)&hL[w][D_IN + lane * 4]  = av;

    // ---- (5) epilogue: out[r][4l..4l+3] = relu(b + sum_k hL[w][k] * Wt[k][4l..]) ----
    const unsigned short* wp = Wt + lane * 4;
    f32x4 o = {0.f, 0.f, 0.f, 0.f};
    #pragma unroll 4
    for (int kc = 0; kc < 128; ++kc) {
        f32x4 hv = *(const f32x4*)&hL[w][kc * 4];   // same addr all lanes: LDS broadcast
        #pragma unroll
        for (int j = 0; j < 4; ++j) {
            uint2 wu = *(const uint2*)(wp + (size_t)(kc * 4 + j) * 256);  // coalesced 8B
            f32x4 wf;
            wf[0] = __uint_as_float(wu.x << 16);
            wf[1] = __uint_as_float(wu.x & 0xFFFF0000u);
            wf[2] = __uint_as_float(wu.y << 16);
            wf[3] = __uint_as_float(wu.y & 0xFFFF0000u);
            o += hv[j] * wf;
        }
    }
    f32x4 bv = *(const f32x4*)(bias + lane * 4);
    o += bv;
    #pragma unroll
    for (int j = 0; j < 4; ++j) o[j] = o[j] > 0.f ? o[j] : 0.f;
    __builtin_nontemporal_store(o, (f32x4*)(out + (size_t)r * D_OUT + lane * 4));
}

// ---------------- launch ----------------
extern "C" void kernel_launch(void* const* d_in, const int* in_sizes, int n_in,
                              void* d_out, int out_size, void* d_ws, size_t ws_size,
                              hipStream_t stream) {
    (void)in_sizes; (void)n_in; (void)out_size; (void)ws_size;
    const float* x   = (const float*)d_in[0];
    const float* adj = (const float*)d_in[1];
    const float* W   = (const float*)d_in[2];
    const float* b   = (const float*)d_in[3];

    unsigned short* Wt = (unsigned short*)d_ws;   // 512x256 bf16 = 256 KB
    float* out = (float*)d_out;

    hipLaunchKernelGGL(k_transw, dim3(512 / 32, 256 / 32), dim3(32, 8), 0, stream, W, Wt);
    hipLaunchKernelGGL(k_fused,  dim3(N_NODES / 4), dim3(256), 0, stream,
                       x, adj, Wt, b, out);
}

// Round 8
// 214.116 us; speedup vs baseline: 1.8724x; 1.8724x over previous
//
#include <hip/hip_runtime.h>
#include <hip/hip_bf16.h>
#include <stdint.h>

// ---------------- problem constants ----------------
#define N_NODES 16384
#define D_IN    256
#define D_OUT   256
#define K_SAMP  10
#define HALF_FLAT (1u << 27)

// JAX PRNG mode: 1 = jax_threefry_partitionable (verified correct R3-R7).
#define JAX_PARTITIONABLE 1

typedef __attribute__((ext_vector_type(4))) float  f32x4;
typedef __attribute__((ext_vector_type(8))) short  bf16x8;
typedef __attribute__((ext_vector_type(4))) int    i32x4;

__device__ __forceinline__ uint32_t rotl32(uint32_t x, int r) {
    return (x << r) | (x >> (32 - r));
}

// Exact replica of jax threefry2x32 noise bits for flat index i = r*16384 + c, key (0,42).
__device__ __forceinline__ uint32_t jax_noise_bits(uint32_t r, uint32_t c) {
    const uint32_t i  = (r << 14) | c;
    const uint32_t k0 = 0u, k1 = 42u;
    const uint32_t k2 = 42u ^ 0x1BD11BDAu;
    uint32_t x0, x1;
#if JAX_PARTITIONABLE
    x0 = 0u;
    x1 = i;
#else
    const bool lo = (i < HALF_FLAT);
    x0 = lo ? i : (i - HALF_FLAT);
    x1 = lo ? (i + HALF_FLAT) : i;
#endif
    x0 += k0; x1 += k1;
#define TFR4(a,b,cc,d) \
    x0 += x1; x1 = rotl32(x1,a);  x1 ^= x0; \
    x0 += x1; x1 = rotl32(x1,b);  x1 ^= x0; \
    x0 += x1; x1 = rotl32(x1,cc); x1 ^= x0; \
    x0 += x1; x1 = rotl32(x1,d);  x1 ^= x0;
    TFR4(13,15,26,6);   x0 += k1; x1 += k2 + 1u;
    TFR4(17,29,16,24);  x0 += k2; x1 += k0 + 2u;
    TFR4(13,15,26,6);   x0 += k0; x1 += k1 + 3u;
    TFR4(17,29,16,24);  x0 += k1; x1 += k2 + 4u;
    TFR4(13,15,26,6);   x0 += k2; x1 += k0 + 5u;
#undef TFR4
#if JAX_PARTITIONABLE
    return x0 ^ x1;
#else
    return (i < HALF_FLAT) ? x0 : x1;
#endif
}

__device__ __forceinline__ unsigned short f2bfbits(float f) {
    __hip_bfloat16 h = __float2bfloat16(f);
    return *(unsigned short*)&h;
}

// ---------------- kernel 1: wave-per-node sample + aggregate → h=[x|agg] bf16 ------------
// 4 waves/block, each wave owns one node. Adjacency streamed with NON-TEMPORAL loads.
// Fast path: integer-OR of 4 words + single ballot per 16B chunk (adj values are exactly
// 0.0f/1.0f, so bits!=0 <=> value!=0). Detailed per-j compaction only when the wave's
// 256-element chunk has any nonzero (P~0.39). Candidate list order is irrelevant:
// selection is by key (noise,col), so compaction just needs the set + count.
// Blocks 0..127 additionally convert W f32 -> Wb bf16 (4KB each) — replaces k_convw.
__global__ __launch_bounds__(256) void k_agg(
    const float* __restrict__ x, const float* __restrict__ adj,
    const float* __restrict__ W, unsigned short* __restrict__ Wb,
    unsigned short* __restrict__ h)
{
    const int t    = threadIdx.x;
    const int lane = t & 63;
    const int w    = t >> 6;
    const int r    = blockIdx.x * 4 + w;

    // fold of k_convw: 128 blocks x 256 threads x 4 floats = 131072 = all of W
    if (blockIdx.x < 128) {
        int i = (blockIdx.x * 256 + t) * 4;
        f32x4 v = *(const f32x4*)(W + i);
        ushort4 u;
        u.x = f2bfbits(v[0]); u.y = f2bfbits(v[1]);
        u.z = f2bfbits(v[2]); u.w = f2bfbits(v[3]);
        *(ushort4*)(Wb + i) = u;
    }

    __shared__ unsigned short candc[4][128];   // per-wave nonzero-column list

    // ---- stream + compact (nt loads, integer fast path) ----
    const i32x4* rowp = (const i32x4*)(adj + (size_t)r * N_NODES);
    int nc = 0;                                 // wave-uniform candidate count
    #pragma unroll 8
    for (int it = 0; it < 64; ++it) {
        i32x4 v = __builtin_nontemporal_load(rowp + it * 64 + lane);
        uint32_t any = (uint32_t)v[0] | (uint32_t)v[1] | (uint32_t)v[2] | (uint32_t)v[3];
        unsigned long long m4 = __ballot(any != 0u);
        if (m4) {
            int cb = (it * 64 + lane) * 4;
            #pragma unroll
            for (int j = 0; j < 4; ++j) {
                unsigned long long mask = __ballot(v[j] != 0);
                if (mask) {
                    if (v[j] != 0) {
                        int below = __builtin_amdgcn_mbcnt_hi(
                            (uint32_t)(mask >> 32),
                            __builtin_amdgcn_mbcnt_lo((uint32_t)mask, 0));
                        int slot = nc + below;
                        if (slot < 128) candc[w][slot] = (unsigned short)(cb + j);
                    }
                    nc += __popcll(mask);
                }
            }
        }
    }
    __syncthreads();                            // makes LDS lists visible wave-internally
    if (nc > 128) nc = 128;                     // P(deg>128) ~ 0 (17 sigma)

    // ---- dense threefry: keys for candidates lane and lane+64 ----
    unsigned long long k0 = 0ull, k1 = 0ull;
    if (lane < nc) {
        uint32_t c   = candc[w][lane];
        uint32_t u23 = jax_noise_bits((uint32_t)r, c) >> 9;   // monotone with uniform float
        k0 = ((((unsigned long long)u23) << 14) | (unsigned long long)(16383u - c)) + 1ull;
    }
    if (64 + lane < nc) {
        uint32_t c   = candc[w][64 + lane];
        uint32_t u23 = jax_noise_bits((uint32_t)r, c) >> 9;
        k1 = ((((unsigned long long)u23) << 14) | (unsigned long long)(16383u - c)) + 1ull;
    }

    // ---- top-K selection (register space) + gather ----
    const int m = nc < K_SAMP ? nc : K_SAMP;
    f32x4 acc = {0.f, 0.f, 0.f, 0.f};
    for (int s = 0; s < m; ++s) {
        unsigned long long my = k0 > k1 ? k0 : k1;
        #pragma unroll
        for (int o = 1; o < 64; o <<= 1) {
            unsigned long long other = __shfl_xor(my, o);
            if (other > my) my = other;
        }
        // keys unique (low 14 bits = distinct column) -> exactly one lane/slot matches
        if (k0 == my) k0 = 0ull; else if (k1 == my) k1 = 0ull;
        const int col = 16383 - (int)((my - 1ull) & 0x3FFFull);
        f32x4 xv = *(const f32x4*)(x + (size_t)col * D_IN + lane * 4);
        acc += xv;
    }
    const float inv = (m > 0) ? 1.0f / (float)m : 0.0f;

    // ---- write h row: [self | agg] bf16 ----
    f32x4 sv = *(const f32x4*)(x + (size_t)r * D_IN + lane * 4);
    ushort4 us, ua;
    us.x = f2bfbits(sv[0]);        us.y = f2bfbits(sv[1]);
    us.z = f2bfbits(sv[2]);        us.w = f2bfbits(sv[3]);
    ua.x = f2bfbits(acc[0] * inv); ua.y = f2bfbits(acc[1] * inv);
    ua.z = f2bfbits(acc[2] * inv); ua.w = f2bfbits(acc[3] * inv);
    unsigned short* hr = h + (size_t)r * (2 * D_IN);
    *(ushort4*)(hr + lane * 4)         = us;
    *(ushort4*)(hr + D_IN + lane * 4)  = ua;
}

// ---------------- kernel 2: out = relu(h @ Wb^T + b), MFMA bf16, f32 out ----------------
// BM=64, BN=64, BK=64 → 1024 blocks (4/CU). Double-buffered LDS, single barrier per
// K-step (issue loads(t+1) → compute(t) → ds_write(t+1) → barrier). Verified R6.
#define BM 64
#define BN 64
#define BK 64

__global__ __launch_bounds__(256) void k_gemm(
    const unsigned short* __restrict__ h, const unsigned short* __restrict__ Wb,
    const float* __restrict__ bias, float* __restrict__ out)
{
    __shared__ short As[2][BM * BK];   // rows XOR-swizzled: byte ^= (row&7)<<4
    __shared__ short Bs[2][BN * BK];

    const int t    = threadIdx.x;
    const int lane = t & 63;
    const int wv   = t >> 6;
    const int wr   = wv >> 1;      // wave row 0..1 (32 rows each)
    const int wc   = wv & 1;       // wave col 0..1 (32 cols each)
    const int m0   = blockIdx.x * BM;
    const int n0   = blockIdx.y * BN;
    const int lr   = lane & 15;
    const int lk   = lane >> 4;

    f32x4 acc[2][2] = {};

    const short* hA = (const short*)h;
    const short* wB = (const short*)Wb;

    const int q0  = t, q1 = t + 256;
    const int r0  = q0 >> 3, c0 = q0 & 7;
    const int r1  = q1 >> 3, c1 = q1 & 7;
    const int ba0 = (r0 * 128 + c0 * 16) ^ ((r0 & 7) << 4);
    const int ba1 = (r1 * 128 + c1 * 16) ^ ((r1 & 7) << 4);

    {
        i32x4 a0 = *(const i32x4*)(hA + (size_t)(m0 + r0) * 512 + c0 * 8);
        i32x4 a1 = *(const i32x4*)(hA + (size_t)(m0 + r1) * 512 + c1 * 8);
        i32x4 b0 = *(const i32x4*)(wB + (size_t)(n0 + r0) * 512 + c0 * 8);
        i32x4 b1 = *(const i32x4*)(wB + (size_t)(n0 + r1) * 512 + c1 * 8);
        *(i32x4*)((char*)&As[0][0] + ba0) = a0;
        *(i32x4*)((char*)&As[0][0] + ba1) = a1;
        *(i32x4*)((char*)&Bs[0][0] + ba0) = b0;
        *(i32x4*)((char*)&Bs[0][0] + ba1) = b1;
    }
    __syncthreads();

    for (int tt = 0; tt < 8; ++tt) {
        const int cur = tt & 1;
        i32x4 a0, a1, b0, b1;
        if (tt < 7) {
            const int k0n = (tt + 1) * BK;
            a0 = *(const i32x4*)(hA + (size_t)(m0 + r0) * 512 + k0n + c0 * 8);
            a1 = *(const i32x4*)(hA + (size_t)(m0 + r1) * 512 + k0n + c1 * 8);
            b0 = *(const i32x4*)(wB + (size_t)(n0 + r0) * 512 + k0n + c0 * 8);
            b1 = *(const i32x4*)(wB + (size_t)(n0 + r1) * 512 + k0n + c1 * 8);
        }

        #pragma unroll
        for (int kk = 0; kk < BK; kk += 32) {
            bf16x8 af[2], bf[2];
            #pragma unroll
            for (int mi = 0; mi < 2; ++mi) {
                int row = wr * 32 + mi * 16 + lr;
                int ba = (row * 128 + (kk + lk * 8) * 2) ^ ((row & 7) << 4);
                af[mi] = *(const bf16x8*)((const char*)&As[cur][0] + ba);
            }
            #pragma unroll
            for (int ni = 0; ni < 2; ++ni) {
                int row = wc * 32 + ni * 16 + lr;
                int ba = (row * 128 + (kk + lk * 8) * 2) ^ ((row & 7) << 4);
                bf[ni] = *(const bf16x8*)((const char*)&Bs[cur][0] + ba);
            }
            #pragma unroll
            for (int mi = 0; mi < 2; ++mi)
                #pragma unroll
                for (int ni = 0; ni < 2; ++ni)
                    acc[mi][ni] = __builtin_amdgcn_mfma_f32_16x16x32_bf16(
                        af[mi], bf[ni], acc[mi][ni], 0, 0, 0);
        }

        if (tt < 7) {
            const int nxt = cur ^ 1;
            *(i32x4*)((char*)&As[nxt][0] + ba0) = a0;
            *(i32x4*)((char*)&As[nxt][0] + ba1) = a1;
            *(i32x4*)((char*)&Bs[nxt][0] + ba0) = b0;
            *(i32x4*)((char*)&Bs[nxt][0] + ba1) = b1;
        }
        __syncthreads();
    }

    // epilogue: C/D layout col=lane&15, row=(lane>>4)*4+j  [verified m89]
    #pragma unroll
    for (int mi = 0; mi < 2; ++mi) {
        #pragma unroll
        for (int ni = 0; ni < 2; ++ni) {
            int col = n0 + wc * 32 + ni * 16 + lr;
            float bv = bias[col];
            #pragma unroll
            for (int j = 0; j < 4; ++j) {
                int rowg = m0 + wr * 32 + mi * 16 + lk * 4 + j;
                float v = acc[mi][ni][j] + bv;
                out[(size_t)rowg * D_OUT + col] = v > 0.0f ? v : 0.0f;
            }
        }
    }
}

// ---------------- launch ----------------
extern "C" void kernel_launch(void* const* d_in, const int* in_sizes, int n_in,
                              void* d_out, int out_size, void* d_ws, size_t ws_size,
                              hipStream_t stream) {
    (void)in_sizes; (void)n_in; (void)out_size; (void)ws_size;
    const float* x   = (const float*)d_in[0];
    const float* adj = (const float*)d_in[1];
    const float* W   = (const float*)d_in[2];
    const float* b   = (const float*)d_in[3];

    unsigned short* hbuf = (unsigned short*)d_ws;                                  // 16.8 MB
    unsigned short* Wb   = (unsigned short*)((char*)d_ws + (size_t)N_NODES * 512 * 2);
    float* out = (float*)d_out;

    hipLaunchKernelGGL(k_agg,  dim3(N_NODES / 4), dim3(256), 0, stream, x, adj, W, Wb, hbuf);
    hipLaunchKernelGGL(k_gemm, dim3(N_NODES / BM, D_OUT / BN), dim3(256), 0, stream,
                       hbuf, Wb, b, out);
}